// Round 1
// baseline (25.137 us; speedup 1.0000x reference)
//
#include <hip/hip_runtime.h>

// GaussianKernelLoss on MI355X.
// Reference: for each (b,n): w = exp(-d_tgt^2/(2*0.1^2)) * (d_tgt <= 0.2);
// per = sum(w * d_prd) / (sum(w) + 1e-8); loss = sum_{vis>=0.5}(per) / (512 + 1e-8).
// Mask => only pixels within radius 0.2 of target contribute; we iterate a
// conservative bounding box (+/-1 px margin) — exact, since w==0 outside.

#define BB 32
#define NN 16
#define HH 256
#define WW 256

__global__ __launch_bounds__(256) void gkl_kernel(
    const float* __restrict__ pred,   // [B,N,2]
    const float* __restrict__ tgt,    // [B,N,2]
    const float* __restrict__ vis,    // [B,N]
    const float* __restrict__ cg,     // [2,H,W]
    float* __restrict__ out)          // [1]
{
    const int bn = blockIdx.x;        // 0..511, one block per (b,n)
    const int t  = threadIdx.x;       // 0..255

    __shared__ float xs[WW];
    __shared__ float ys[HH];
    __shared__ float s_num[4], s_den[4];

    // coord_grid[0, 0, j] = x_j (same for all rows); coord_grid[1, i, 0] = y_i.
    xs[t] = cg[t];
    ys[t] = cg[HH * WW + t * WW];
    __syncthreads();

    // Landmarks with visibility < 0.5 contribute exactly 0 — skip the block.
    const float v = vis[bn];
    if (v < 0.5f) return;

    const float tx = tgt[bn * 2 + 0], ty = tgt[bn * 2 + 1];
    const float px = pred[bn * 2 + 0], py = pred[bn * 2 + 1];

    // Conservative bbox: pixels with |x_j - tx| > RADIUS or |y_i - ty| > RADIUS
    // have w == 0. Grid spacing is ~1/255; pad by 1 px for FP safety.
    const float RADIUS = 0.2f;
    int j_lo = max(0,      (int)floorf((tx - RADIUS) * 255.0f) - 1);
    int j_hi = min(WW - 1, (int)ceilf ((tx + RADIUS) * 255.0f) + 1);
    int i_lo = max(0,      (int)floorf((ty - RADIUS) * 255.0f) - 1);
    int i_hi = min(HH - 1, (int)ceilf ((ty + RADIUS) * 255.0f) + 1);

    const int bw   = j_hi - j_lo + 1;
    const int bh   = i_hi - i_lo + 1;
    const int npix = bw * bh;

    float num = 0.0f, den = 0.0f;
    for (int p = t; p < npix; p += 256) {
        const int i = i_lo + p / bw;
        const int j = j_lo + p % bw;
        const float x = xs[j], y = ys[i];
        const float dtx = x - tx, dty = y - ty;
        const float d2t = dtx * dtx + dty * dty;
        const float dt  = sqrtf(d2t);
        if (dt <= RADIUS) {
            const float w   = expf(-50.0f * d2t);   // 1/(2*sigma^2) = 50
            const float dpx = x - px, dpy = y - py;
            const float dp  = sqrtf(dpx * dpx + dpy * dpy);
            num = fmaf(w, dp, num);
            den += w;
        }
    }

    // Wave (64-lane) butterfly reduce, then cross-wave via LDS.
    for (int off = 32; off > 0; off >>= 1) {
        num += __shfl_down(num, off);
        den += __shfl_down(den, off);
    }
    const int wave = t >> 6;
    if ((t & 63) == 0) { s_num[wave] = num; s_den[wave] = den; }
    __syncthreads();
    if (t == 0) {
        float n_tot = s_num[0] + s_num[1] + s_num[2] + s_num[3];
        float d_tot = s_den[0] + s_den[1] + s_den[2] + s_den[3];
        const float per = n_tot / (d_tot + 1e-8f);
        // total / (B*N + 1e-8); in fp32, 512 + 1e-8 == 512.
        atomicAdd(out, per * (1.0f / 512.0f));
    }
}

extern "C" void kernel_launch(void* const* d_in, const int* in_sizes, int n_in,
                              void* d_out, int out_size, void* d_ws, size_t ws_size,
                              hipStream_t stream) {
    const float* pred = (const float*)d_in[0];
    const float* tgt  = (const float*)d_in[1];
    const float* vis  = (const float*)d_in[2];
    const float* cg   = (const float*)d_in[3];
    float* out = (float*)d_out;

    hipMemsetAsync(out, 0, sizeof(float), stream);
    gkl_kernel<<<BB * NN, 256, 0, stream>>>(pred, tgt, vis, cg, out);
}

// Round 2
// 17.964 us; speedup vs baseline: 1.3993x; 1.3993x over previous
//
#include <hip/hip_runtime.h>

// GaussianKernelLoss on MI355X — two-phase, no atomics, no memset.
// Phase 1: one 256-thread block per (b,n). Separable precompute:
//   per-col float4 {dxt^2, exp(-50*dxt^2), dxp^2, 0}
//   per-row float4 {dyt^2, exp(-50*dyt^2), dyp^2, 0}
// inner loop per pixel: d2t = cx+rx; mask sqrt(d2t)<=0.2; w = cw*rw;
//   dp = sqrt(cz+rz); num += w*dp; den += w.
// Phase 2: single block sums the 512 per-landmark values -> out (plain store).

#define BB 32
#define NN 16
#define HH 256
#define WW 256
#define BN (BB * NN)

__global__ __launch_bounds__(256) void gkl_phase1(
    const float* __restrict__ pred,   // [B,N,2]
    const float* __restrict__ tgt,    // [B,N,2]
    const float* __restrict__ vis,    // [B,N]
    const float* __restrict__ cg,     // [2,H,W]
    float* __restrict__ ws)           // [BN] per-landmark values
{
    const int bn = blockIdx.x;        // one block per (b,n)
    const int t  = threadIdx.x;

    // Invisible landmarks contribute exactly 0.
    if (vis[bn] < 0.5f) { if (t == 0) ws[bn] = 0.0f; return; }

    const float tx = tgt[bn * 2 + 0], ty = tgt[bn * 2 + 1];
    const float px = pred[bn * 2 + 0], py = pred[bn * 2 + 1];

    // Conservative bbox (w == 0 outside radius 0.2; +/-1 px FP margin).
    const float R = 0.2f;
    const int j_lo = max(0,      (int)floorf((tx - R) * 255.0f) - 1);
    const int j_hi = min(WW - 1, (int)ceilf ((tx + R) * 255.0f) + 1);
    const int i_lo = max(0,      (int)floorf((ty - R) * 255.0f) - 1);
    const int i_hi = min(HH - 1, (int)ceilf ((ty + R) * 255.0f) + 1);
    const int bw = j_hi - j_lo + 1;   // <= 106
    const int bh = i_hi - i_lo + 1;   // <= 106

    __shared__ float4 colA[128];
    __shared__ float4 rowA[128];
    __shared__ float  s_n[4], s_d[4];

    // Separable precompute: threads 0..127 columns, 128..255 rows.
    if (t < 128) {
        if (t < bw) {
            const float x   = cg[j_lo + t];            // x-coords: row 0 of plane 0
            const float dxt = x - tx, dxp = x - px;
            colA[t] = make_float4(dxt * dxt, expf(-50.0f * dxt * dxt),
                                  dxp * dxp, 0.0f);
        }
    } else {
        const int r = t - 128;
        if (r < bh) {
            const float y   = cg[HH * WW + (i_lo + r) * WW];  // y-coords: col 0 of plane 1
            const float dyt = y - ty, dyp = y - py;
            rowA[r] = make_float4(dyt * dyt, expf(-50.0f * dyt * dyt),
                                  dyp * dyp, 0.0f);
        }
    }
    __syncthreads();

    const int lane = t & 63;
    const int wid  = t >> 6;

    float num = 0.0f, den = 0.0f;
    for (int r = wid; r < bh; r += 4) {
        const float4 rv = rowA[r];                 // wave-uniform: LDS broadcast
        for (int c = lane; c < bw; c += 64) {
            const float4 cv = colA[c];
            const float d2t = cv.x + rv.x;
            const float dt  = sqrtf(d2t);
            float w = cv.y * rv.y;
            w = (dt <= 0.2f) ? w : 0.0f;           // exact reference mask
            const float dp = sqrtf(cv.z + rv.z);
            num = fmaf(w, dp, num);
            den += w;
        }
    }

    // Wave butterfly reduce, then cross-wave via LDS.
    for (int off = 32; off > 0; off >>= 1) {
        num += __shfl_down(num, off);
        den += __shfl_down(den, off);
    }
    if (lane == 0) { s_n[wid] = num; s_d[wid] = den; }
    __syncthreads();
    if (t == 0) {
        const float n_tot = s_n[0] + s_n[1] + s_n[2] + s_n[3];
        const float d_tot = s_d[0] + s_d[1] + s_d[2] + s_d[3];
        ws[bn] = n_tot / (d_tot + 1e-8f);
    }
}

__global__ __launch_bounds__(512) void gkl_phase2(
    const float* __restrict__ ws, float* __restrict__ out)
{
    const int t = threadIdx.x;       // 512 threads = 8 waves
    float v = ws[t];
    for (int off = 32; off > 0; off >>= 1) v += __shfl_down(v, off);
    __shared__ float s[8];
    if ((t & 63) == 0) s[t >> 6] = v;
    __syncthreads();
    if (t == 0) {
        float tot = 0.0f;
        #pragma unroll
        for (int i = 0; i < 8; ++i) tot += s[i];
        out[0] = tot * (1.0f / 512.0f);   // fp32(512 + 1e-8) == 512
    }
}

extern "C" void kernel_launch(void* const* d_in, const int* in_sizes, int n_in,
                              void* d_out, int out_size, void* d_ws, size_t ws_size,
                              hipStream_t stream) {
    const float* pred = (const float*)d_in[0];
    const float* tgt  = (const float*)d_in[1];
    const float* vis  = (const float*)d_in[2];
    const float* cg   = (const float*)d_in[3];
    float* ws  = (float*)d_ws;
    float* out = (float*)d_out;

    gkl_phase1<<<BN, 256, 0, stream>>>(pred, tgt, vis, cg, ws);
    gkl_phase2<<<1, 512, 0, stream>>>(ws, out);
}